// Round 3
// baseline (220.597 us; speedup 1.0000x reference)
//
#include <hip/hip_runtime.h>

typedef __attribute__((ext_vector_type(8))) __bf16 bf16x8;
typedef __attribute__((ext_vector_type(4))) float f32x4;
typedef __attribute__((ext_vector_type(8))) unsigned short us8;
typedef __attribute__((ext_vector_type(4))) unsigned short us4;

#define NTOK 98
#define NPAD 112
#define CDIM 192
#define NH 6
#define HD 32
#define NWIN 64
#define BWIN 512
#define MROWS (BWIN * NTOK)     // 50176
#define QKVN (3 * CDIM)         // 576
#define SCALE 0.17677669529663687f

__device__ __forceinline__ unsigned short f2b(float f) {
  unsigned u = __builtin_bit_cast(unsigned, f);
  u += 0x7FFFu + ((u >> 16) & 1u);   // RNE; inputs are finite
  return (unsigned short)(u >> 16);
}

__device__ __forceinline__ bf16x8 ldfrag(const unsigned short* p) {
  return __builtin_bit_cast(bf16x8, *(const us8*)p);
}

// ---------------- K0: bm[w][h][i][j] = bias_table[rel_index[i][j]][h] + mask[w][i][j]
__global__ __launch_bounds__(256) void k_biasmask(
    const float* __restrict__ mask, const float* __restrict__ table,
    const int* __restrict__ relidx, float* __restrict__ bm) {
  int idx = blockIdx.x * 256 + threadIdx.x;
  if (idx >= NWIN * NH * NTOK * NTOK) return;
  int j = idx % NTOK;
  int t = idx / NTOK;
  int i = t % NTOK;
  t /= NTOK;
  int h = t % NH;
  int w = t / NH;
  bm[idx] = table[relidx[i * NTOK + j] * NH + h] + mask[(w * NTOK + i) * NTOK + j];
}

// ---------------- K1: qkv = x @ qkv_w^T + qkv_b  (q portion pre-scaled), bf16 out
// A-stationary: block owns 128 rows, K=192 fully staged; loops 9 N-tiles of 64.
__global__ __launch_bounds__(256) void k_qkv(
    const float* __restrict__ x, const float* __restrict__ w,
    const float* __restrict__ bias, unsigned short* __restrict__ qkv) {
  __shared__ unsigned short As[128 * 200];   // stride 200: 2-way bank max
  __shared__ unsigned short Bs[64 * 200];
  const int tid = threadIdx.x;
  const int m0 = blockIdx.x * 128;
  for (int it = 0; it < 24; ++it) {          // 6144 float4 = 128x192 fp32 -> bf16
    int q = it * 256 + tid;
    int row = q / 48, c4 = q - row * 48;
    float4 v = *(const float4*)(x + (m0 + row) * CDIM + c4 * 4);
    us4 u = {f2b(v.x), f2b(v.y), f2b(v.z), f2b(v.w)};
    *(us4*)&As[row * 200 + c4 * 4] = u;
  }
  const int lane = tid & 63;
  const int l15 = lane & 15, hi = lane >> 4;
  const int wr = (tid >> 6) >> 1, wc = (tid >> 6) & 1;
  __syncthreads();
  for (int j = 0; j < 9; ++j) {
    for (int it = 0; it < 12; ++it) {        // 3072 float4 = 64x192 of W
      int q = it * 256 + tid;
      int row = q / 48, c4 = q - row * 48;
      float4 v = *(const float4*)(w + (j * 64 + row) * CDIM + c4 * 4);
      us4 u = {f2b(v.x), f2b(v.y), f2b(v.z), f2b(v.w)};
      *(us4*)&Bs[row * 200 + c4 * 4] = u;
    }
    __syncthreads();
    f32x4 acc[4][2];
#pragma unroll
    for (int fr = 0; fr < 4; ++fr) { acc[fr][0] = (f32x4)0.f; acc[fr][1] = (f32x4)0.f; }
#pragma unroll
    for (int ks = 0; ks < 6; ++ks) {
      int k0 = ks * 32 + hi * 8;
      bf16x8 b0 = ldfrag(&Bs[(wc * 32 + l15) * 200 + k0]);
      bf16x8 b1 = ldfrag(&Bs[(wc * 32 + 16 + l15) * 200 + k0]);
#pragma unroll
      for (int fr = 0; fr < 4; ++fr) {
        bf16x8 a = ldfrag(&As[(wr * 64 + fr * 16 + l15) * 200 + k0]);
        acc[fr][0] = __builtin_amdgcn_mfma_f32_16x16x32_bf16(a, b0, acc[fr][0], 0, 0, 0);
        acc[fr][1] = __builtin_amdgcn_mfma_f32_16x16x32_bf16(a, b1, acc[fr][1], 0, 0, 0);
      }
    }
    __syncthreads();
#pragma unroll
    for (int fr = 0; fr < 4; ++fr)
#pragma unroll
      for (int fc = 0; fc < 2; ++fc)
#pragma unroll
        for (int r = 0; r < 4; ++r) {
          int row = m0 + wr * 64 + fr * 16 + hi * 4 + r;
          int col = j * 64 + wc * 32 + fc * 16 + l15;
          float v = acc[fr][fc][r] + bias[col];
          if (col < CDIM) v *= SCALE;        // scale folded into q
          qkv[row * QKVN + col] = f2b(v);
        }
  }
}

// ---------------- K2: attention per (b,h). 7 waves; wave r owns rows [16r,16r+16).
__global__ __launch_bounds__(448) void k_attn(
    const unsigned short* __restrict__ qkv, const float* __restrict__ bm,
    unsigned short* __restrict__ ao) {
  __shared__ unsigned short Ks[NPAD * 40];   // K rows [n'][d], stride 40
  __shared__ unsigned short Vt[32 * 136];    // V^T [d][n'], stride 136, n'>=98 zeroed
  __shared__ unsigned short P[NPAD * 136];   // softmax probs bf16, cols>=112 zeroed
  const int tid = threadIdx.x;
  const int h = blockIdx.x % NH;
  const int b = blockIdx.x / NH;
  const int wnd = b & (NWIN - 1);
  const int lane = tid & 63, wv = tid >> 6;
  const int l15 = lane & 15, hi = lane >> 4;
  {
    int row = tid >> 2, q = tid & 3;         // 112 rows x 4 quarters = 448 threads
    us8 kv = (us8)0;
    if (row < NTOK)
      kv = *(const us8*)(qkv + (b * NTOK + row) * QKVN + CDIM + h * HD + q * 8);
    *(us8*)&Ks[row * 40 + q * 8] = kv;
    if (row < NTOK) {
      us8 vv = *(const us8*)(qkv + (b * NTOK + row) * QKVN + 2 * CDIM + h * HD + q * 8);
#pragma unroll
      for (int i = 0; i < 8; ++i) Vt[(q * 8 + i) * 136 + row] = vv[i];
    }
    for (int i = tid; i < 32 * 38; i += 448) {       // zero Vt n' in [98,136)
      int dd = i / 38, n = NTOK + (i - dd * 38);
      Vt[dd * 136 + n] = 0;
    }
    for (int i = tid; i < NPAD * 16; i += 448)       // zero P cols [112,128)
      P[(i >> 4) * 136 + 112 + (i & 15)] = 0;
  }
  int qn = wv * 16 + l15;
  us8 qu = (us8)0;
  if (qn < NTOK)
    qu = *(const us8*)(qkv + (b * NTOK + qn) * QKVN + h * HD + hi * 8);
  bf16x8 qf = __builtin_bit_cast(bf16x8, qu);
  __syncthreads();
  // S = (scaled Q) K^T; one 16x16x32 MFMA per column tile
  f32x4 sacc[7];
#pragma unroll
  for (int tc = 0; tc < 7; ++tc) {
    bf16x8 kb = ldfrag(&Ks[(tc * 16 + l15) * 40 + hi * 8]);
    sacc[tc] = __builtin_amdgcn_mfma_f32_16x16x32_bf16(qf, kb, (f32x4)0.f, 0, 0, 0);
  }
  const float* bmp = bm + (wnd * NH + h) * NTOK * NTOK;
  float rsum[4];
#pragma unroll
  for (int r = 0; r < 4; ++r) {
    int row = wv * 16 + hi * 4 + r;
    float sv[7];
    float m = -1e30f;
#pragma unroll
    for (int tc = 0; tc < 7; ++tc) {
      int col = tc * 16 + l15;
      float val = -1e30f;
      if (col < NTOK && row < NTOK) val = sacc[tc][r] + bmp[row * NTOK + col];
      sv[tc] = val;
      m = fmaxf(m, val);
    }
#pragma unroll
    for (int off = 1; off < 16; off <<= 1) m = fmaxf(m, __shfl_xor(m, off));
    float s = 0.f;
#pragma unroll
    for (int tc = 0; tc < 7; ++tc) {
      float e = __expf(sv[tc] - m);          // cols>=98 -> exp(-inf) = 0 exactly
      s += e;
      P[row * 136 + tc * 16 + l15] = f2b(e);
    }
#pragma unroll
    for (int off = 1; off < 16; off <<= 1) s += __shfl_xor(s, off);
    rsum[r] = s;
  }
  // O = P V (own-wave rows only; same-wave LDS ops are in-order, no barrier needed)
  f32x4 oacc[2];
  oacc[0] = (f32x4)0.f; oacc[1] = (f32x4)0.f;
#pragma unroll
  for (int ks = 0; ks < 4; ++ks) {
    int k0 = ks * 32 + hi * 8;
    bf16x8 pa = ldfrag(&P[(wv * 16 + l15) * 136 + k0]);
#pragma unroll
    for (int tc = 0; tc < 2; ++tc) {
      bf16x8 vb = ldfrag(&Vt[(tc * 16 + l15) * 136 + k0]);
      oacc[tc] = __builtin_amdgcn_mfma_f32_16x16x32_bf16(pa, vb, oacc[tc], 0, 0, 0);
    }
  }
#pragma unroll
  for (int tc = 0; tc < 2; ++tc)
#pragma unroll
    for (int r = 0; r < 4; ++r) {
      int row = wv * 16 + hi * 4 + r;
      if (row < NTOK) {
        float v = oacc[tc][r] / rsum[r];
        ao[(b * NTOK + row) * CDIM + h * HD + tc * 16 + l15] = f2b(v);
      }
    }
}

// ---------------- K3: out = ao @ out_w^T + out_b (fp32 out)
__global__ __launch_bounds__(256) void k_proj(
    const unsigned short* __restrict__ a, const float* __restrict__ w,
    const float* __restrict__ bias, float* __restrict__ out) {
  __shared__ unsigned short As[128 * 200];
  __shared__ unsigned short Bs[64 * 200];
  const int tid = threadIdx.x;
  const int m0 = blockIdx.x * 128;
  for (int it = 0; it < 12; ++it) {          // 3072 us8 = 128x192 bf16
    int q = it * 256 + tid;
    int row = q / 24, c8 = q - row * 24;
    *(us8*)&As[row * 200 + c8 * 8] = *(const us8*)(a + (m0 + row) * CDIM + c8 * 8);
  }
  const int lane = tid & 63;
  const int l15 = lane & 15, hi = lane >> 4;
  const int wr = (tid >> 6) >> 1, wc = (tid >> 6) & 1;
  __syncthreads();
  for (int j = 0; j < 3; ++j) {
    for (int it = 0; it < 12; ++it) {
      int q = it * 256 + tid;
      int row = q / 48, c4 = q - row * 48;
      float4 v = *(const float4*)(w + (j * 64 + row) * CDIM + c4 * 4);
      us4 u = {f2b(v.x), f2b(v.y), f2b(v.z), f2b(v.w)};
      *(us4*)&Bs[row * 200 + c4 * 4] = u;
    }
    __syncthreads();
    f32x4 acc[4][2];
#pragma unroll
    for (int fr = 0; fr < 4; ++fr) { acc[fr][0] = (f32x4)0.f; acc[fr][1] = (f32x4)0.f; }
#pragma unroll
    for (int ks = 0; ks < 6; ++ks) {
      int k0 = ks * 32 + hi * 8;
      bf16x8 b0 = ldfrag(&Bs[(wc * 32 + l15) * 200 + k0]);
      bf16x8 b1 = ldfrag(&Bs[(wc * 32 + 16 + l15) * 200 + k0]);
#pragma unroll
      for (int fr = 0; fr < 4; ++fr) {
        bf16x8 aa = ldfrag(&As[(wr * 64 + fr * 16 + l15) * 200 + k0]);
        acc[fr][0] = __builtin_amdgcn_mfma_f32_16x16x32_bf16(aa, b0, acc[fr][0], 0, 0, 0);
        acc[fr][1] = __builtin_amdgcn_mfma_f32_16x16x32_bf16(aa, b1, acc[fr][1], 0, 0, 0);
      }
    }
    __syncthreads();
#pragma unroll
    for (int fr = 0; fr < 4; ++fr)
#pragma unroll
      for (int fc = 0; fc < 2; ++fc)
#pragma unroll
        for (int r = 0; r < 4; ++r) {
          int row = m0 + wr * 64 + fr * 16 + hi * 4 + r;
          int col = j * 64 + wc * 32 + fc * 16 + l15;
          out[row * CDIM + col] = acc[fr][fc][r] + bias[col];
        }
  }
}

extern "C" void kernel_launch(void* const* d_in, const int* in_sizes, int n_in,
                              void* d_out, int out_size, void* d_ws, size_t ws_size,
                              hipStream_t stream) {
  const float* x      = (const float*)d_in[0];
  const float* mask   = (const float*)d_in[1];
  const float* qkv_w  = (const float*)d_in[2];
  const float* qkv_b  = (const float*)d_in[3];
  const float* out_w  = (const float*)d_in[4];
  const float* out_b  = (const float*)d_in[5];
  const float* table  = (const float*)d_in[6];
  const int*   relidx = (const int*)d_in[7];
  float* out = (float*)d_out;
  char* ws = (char*)d_ws;

  const size_t bm_bytes  = (size_t)NWIN * NH * NTOK * NTOK * 4;  // 14,751,744
  const size_t qkv_bytes = (size_t)MROWS * QKVN * 2;             // 57,802,752
  float* bm = (float*)ws;
  unsigned short* qkvp = (unsigned short*)(ws + bm_bytes);
  unsigned short* aop  = (unsigned short*)(ws + bm_bytes + qkv_bytes);

  int bmtot = NWIN * NH * NTOK * NTOK;
  k_biasmask<<<(bmtot + 255) / 256, 256, 0, stream>>>(mask, table, relidx, bm);
  k_qkv<<<MROWS / 128, 256, 0, stream>>>(x, qkv_w, qkv_b, qkvp);
  k_attn<<<BWIN * NH, 448, 0, stream>>>(qkvp, bm, aop);
  k_proj<<<MROWS / 128, 256, 0, stream>>>(aop, out_w, out_b, out);
}

// Round 6
// 198.247 us; speedup vs baseline: 1.1127x; 1.1127x over previous
//
#include <hip/hip_runtime.h>

typedef __attribute__((ext_vector_type(8))) __bf16 bf16x8;
typedef __attribute__((ext_vector_type(4))) float f32x4;
typedef __attribute__((ext_vector_type(8))) unsigned short us8;
typedef __attribute__((ext_vector_type(4))) unsigned short us4;

#define NTOK 98
#define NPAD 112
#define CDIM 192
#define NH 6
#define HD 32
#define NWIN 64
#define BWIN 512
#define MROWS (BWIN * NTOK)     // 50176
#define QKVN (3 * CDIM)         // 576
#define NN (NTOK * NTOK)        // 9604
#define SCALE 0.17677669529663687f

#define PREP_BIAS (NH * NN)        // 57624
#define PREP_WQ (QKVN * CDIM)      // 110592
#define PREP_WO (CDIM * CDIM)      // 36864
#define PREP_TOT (PREP_BIAS + PREP_WQ + PREP_WO)

__device__ __forceinline__ unsigned short f2b(float f) {
  unsigned u = __builtin_bit_cast(unsigned, f);
  u += 0x7FFFu + ((u >> 16) & 1u);   // RNE; inputs are finite
  return (unsigned short)(u >> 16);
}

__device__ __forceinline__ bf16x8 ldfrag(const unsigned short* p) {
  return __builtin_bit_cast(bf16x8, *(const us8*)p);
}

// ---------------- K0: prep — biasHT[h][i][j] = table[relidx[i*98+j]*6+h];
//                        wqb/wob = bf16(qkv_w / out_w)
__global__ __launch_bounds__(256) void k_prep(
    const float* __restrict__ table, const int* __restrict__ relidx,
    const float* __restrict__ wq, const float* __restrict__ wo,
    float* __restrict__ biasHT, unsigned short* __restrict__ wqb,
    unsigned short* __restrict__ wob) {
  int idx = blockIdx.x * 256 + threadIdx.x;
  if (idx < PREP_BIAS) {
    int h = idx / NN, ij = idx - h * NN;
    biasHT[idx] = table[relidx[ij] * NH + h];
    return;
  }
  int i2 = idx - PREP_BIAS;
  if (i2 < PREP_WQ) { if (i2 >= 0) wqb[i2] = f2b(wq[i2]); return; }
  int i3 = i2 - PREP_WQ;
  if (i3 < PREP_WO) wob[i3] = f2b(wo[i3]);
}

// ---------------- K1: qkv = x @ qkv_w^T + qkv_b (q pre-scaled), bf16, PLANE layout:
// qkv[((t*6+head)*MROWS + row)*32 + d], t in {q,k,v}
__global__ __launch_bounds__(256) void k_qkv(
    const float* __restrict__ x, const unsigned short* __restrict__ wqb,
    const float* __restrict__ bias, unsigned short* __restrict__ qkv) {
  __shared__ unsigned short As[128 * 200];   // stride 200: 2-way bank max
  __shared__ unsigned short Bs[64 * 200];
  const int tid = threadIdx.x;
  const int m0 = blockIdx.x * 128;
  for (int it = 0; it < 24; ++it) {          // 6144 float4 = 128x192 fp32 -> bf16
    int q = it * 256 + tid;
    int row = q / 48, c4 = q - row * 48;
    float4 v = *(const float4*)(x + (m0 + row) * CDIM + c4 * 4);
    us4 u = {f2b(v.x), f2b(v.y), f2b(v.z), f2b(v.w)};
    *(us4*)&As[row * 200 + c4 * 4] = u;
  }
  const int lane = tid & 63;
  const int l15 = lane & 15, hi = lane >> 4;
  const int wr = (tid >> 6) >> 1, wc = (tid >> 6) & 1;
  __syncthreads();
  for (int j = 0; j < 9; ++j) {
    for (int it = 0; it < 6; ++it) {         // 1536 us8 = 64x192 bf16 of W
      int q = it * 256 + tid;
      int row = q / 24, c8 = q - row * 24;
      *(us8*)&Bs[row * 200 + c8 * 8] = *(const us8*)(wqb + (j * 64 + row) * CDIM + c8 * 8);
    }
    __syncthreads();
    f32x4 acc[4][2];
#pragma unroll
    for (int fr = 0; fr < 4; ++fr) { acc[fr][0] = (f32x4)0.f; acc[fr][1] = (f32x4)0.f; }
#pragma unroll
    for (int ks = 0; ks < 6; ++ks) {
      int k0 = ks * 32 + hi * 8;
      bf16x8 b0 = ldfrag(&Bs[(wc * 32 + l15) * 200 + k0]);
      bf16x8 b1 = ldfrag(&Bs[(wc * 32 + 16 + l15) * 200 + k0]);
#pragma unroll
      for (int fr = 0; fr < 4; ++fr) {
        bf16x8 a = ldfrag(&As[(wr * 64 + fr * 16 + l15) * 200 + k0]);
        acc[fr][0] = __builtin_amdgcn_mfma_f32_16x16x32_bf16(a, b0, acc[fr][0], 0, 0, 0);
        acc[fr][1] = __builtin_amdgcn_mfma_f32_16x16x32_bf16(a, b1, acc[fr][1], 0, 0, 0);
      }
    }
    __syncthreads();
#pragma unroll
    for (int fr = 0; fr < 4; ++fr)
#pragma unroll
      for (int fc = 0; fc < 2; ++fc) {
        int colb = j * 64 + wc * 32 + fc * 16;         // 16-aligned; same (t,head) for all l15
        int t = (colb >= 2 * CDIM) ? 2 : (colb >= CDIM ? 1 : 0);
        int head = (colb >> 5) - t * NH;
        int d = (colb & 31) + l15;
        long pbase = ((long)(t * NH + head) * MROWS) * 32 + d;
#pragma unroll
        for (int r = 0; r < 4; ++r) {
          int row = m0 + wr * 64 + fr * 16 + hi * 4 + r;
          float v = acc[fr][fc][r] + bias[colb + l15];
          if (t == 0) v *= SCALE;                      // scale folded into q
          qkv[pbase + (long)row * 32] = f2b(v);
        }
      }
  }
}

// ---------------- K2: attention per (b,h). 7 waves; wave r owns rows [16r,16r+16).
__global__ __launch_bounds__(448) void k_attn(
    const unsigned short* __restrict__ qkv, const float* __restrict__ biasHT,
    const float* __restrict__ mask, unsigned short* __restrict__ ao) {
  __shared__ unsigned short Ks[NPAD * 40];   // K rows [n'][d], stride 40
  __shared__ unsigned short Vt[32 * 136];    // V^T [d][n'], stride 136, n'>=98 zeroed
  __shared__ unsigned short P[NPAD * 136];   // probs bf16, cols>=112 zeroed
  const int tid = threadIdx.x;
  const int h = blockIdx.x % NH;
  const int b = blockIdx.x / NH;
  const int wnd = b & (NWIN - 1);
  const int lane = tid & 63, wv = tid >> 6;
  const int l15 = lane & 15, hi = lane >> 4;
  const long rb = (long)b * NTOK;
  const unsigned short* qp = qkv + ((long)h * MROWS + rb) * 32;
  const unsigned short* kp = qkv + ((long)(NH + h) * MROWS + rb) * 32;
  const unsigned short* vp = qkv + ((long)(2 * NH + h) * MROWS + rb) * 32;
  {
    int row = tid >> 2, q = tid & 3;         // 112 rows x 4 quarters = 448 threads
    us8 kv = (us8)0;
    if (row < NTOK) kv = *(const us8*)(kp + row * 32 + q * 8);
    *(us8*)&Ks[row * 40 + q * 8] = kv;
    if (row < NTOK) {
      us8 vv = *(const us8*)(vp + row * 32 + q * 8);
#pragma unroll
      for (int i = 0; i < 8; ++i) Vt[(q * 8 + i) * 136 + row] = vv[i];
    }
    for (int i = tid; i < 32 * 38; i += 448) {       // zero Vt n' in [98,136)
      int dd = i / 38, n = NTOK + (i - dd * 38);
      Vt[dd * 136 + n] = 0;
    }
    for (int i = tid; i < NPAD * 16; i += 448)       // zero P cols [112,128)
      P[(i >> 4) * 136 + 112 + (i & 15)] = 0;
  }
  int qn = wv * 16 + l15;
  us8 qu = (us8)0;
  if (qn < NTOK) qu = *(const us8*)(qp + qn * 32 + hi * 8);
  bf16x8 qf = __builtin_bit_cast(bf16x8, qu);
  __syncthreads();
  // S = (scaled Q) K^T; one 16x16x32 MFMA per column tile
  f32x4 sacc[7];
#pragma unroll
  for (int tc = 0; tc < 7; ++tc) {
    bf16x8 kb = ldfrag(&Ks[(tc * 16 + l15) * 40 + hi * 8]);
    sacc[tc] = __builtin_amdgcn_mfma_f32_16x16x32_bf16(qf, kb, (f32x4)0.f, 0, 0, 0);
  }
  const float* bp = biasHT + h * NN;
  const float* mp = mask + wnd * NN;
  float rsum[4];
#pragma unroll
  for (int r = 0; r < 4; ++r) {
    int row = wv * 16 + hi * 4 + r;
    float sv[7];
    float m = -1e30f;
#pragma unroll
    for (int tc = 0; tc < 7; ++tc) {
      int col = tc * 16 + l15;
      float val = -1e30f;
      if (col < NTOK && row < NTOK) {
        int o = row * NTOK + col;
        val = (sacc[tc][r] + bp[o]) + mp[o];   // match ref add order
      }
      sv[tc] = val;
      m = fmaxf(m, val);
    }
#pragma unroll
    for (int off = 1; off < 16; off <<= 1) m = fmaxf(m, __shfl_xor(m, off));
    float s = 0.f;
#pragma unroll
    for (int tc = 0; tc < 7; ++tc) {
      float e = __expf(sv[tc] - m);          // cols>=98 -> exp(-inf) = 0 exactly
      s += e;
      P[row * 136 + tc * 16 + l15] = f2b(e);
    }
#pragma unroll
    for (int off = 1; off < 16; off <<= 1) s += __shfl_xor(s, off);
    rsum[r] = s;
  }
  // O = P V (own-wave rows only; same-wave LDS ops are in-order, no barrier needed)
  f32x4 oacc[2];
  oacc[0] = (f32x4)0.f; oacc[1] = (f32x4)0.f;
#pragma unroll
  for (int ks = 0; ks < 4; ++ks) {
    int k0 = ks * 32 + hi * 8;
    bf16x8 pa = ldfrag(&P[(wv * 16 + l15) * 136 + k0]);
#pragma unroll
    for (int tc = 0; tc < 2; ++tc) {
      bf16x8 vb = ldfrag(&Vt[(tc * 16 + l15) * 136 + k0]);
      oacc[tc] = __builtin_amdgcn_mfma_f32_16x16x32_bf16(pa, vb, oacc[tc], 0, 0, 0);
    }
  }
#pragma unroll
  for (int tc = 0; tc < 2; ++tc)
#pragma unroll
    for (int r = 0; r < 4; ++r) {
      int row = wv * 16 + hi * 4 + r;
      if (row < NTOK) {
        float v = oacc[tc][r] / rsum[r];
        ao[(rb + row) * CDIM + h * HD + tc * 16 + l15] = f2b(v);
      }
    }
}

// ---------------- K3: out = ao @ out_w^T + out_b (fp32 out)
__global__ __launch_bounds__(256) void k_proj(
    const unsigned short* __restrict__ a, const unsigned short* __restrict__ wob,
    const float* __restrict__ bias, float* __restrict__ out) {
  __shared__ unsigned short As[128 * 200];
  __shared__ unsigned short Bs[64 * 200];
  const int tid = threadIdx.x;
  const int m0 = blockIdx.x * 128;
  for (int it = 0; it < 12; ++it) {          // 3072 us8 = 128x192 bf16
    int q = it * 256 + tid;
    int row = q / 24, c8 = q - row * 24;
    *(us8*)&As[row * 200 + c8 * 8] = *(const us8*)(a + (m0 + row) * CDIM + c8 * 8);
  }
  const int lane = tid & 63;
  const int l15 = lane & 15, hi = lane >> 4;
  const int wr = (tid >> 6) >> 1, wc = (tid >> 6) & 1;
  __syncthreads();
  for (int j = 0; j < 3; ++j) {
    for (int it = 0; it < 6; ++it) {
      int q = it * 256 + tid;
      int row = q / 24, c8 = q - row * 24;
      *(us8*)&Bs[row * 200 + c8 * 8] = *(const us8*)(wob + (j * 64 + row) * CDIM + c8 * 8);
    }
    __syncthreads();
    f32x4 acc[4][2];
#pragma unroll
    for (int fr = 0; fr < 4; ++fr) { acc[fr][0] = (f32x4)0.f; acc[fr][1] = (f32x4)0.f; }
#pragma unroll
    for (int ks = 0; ks < 6; ++ks) {
      int k0 = ks * 32 + hi * 8;
      bf16x8 b0 = ldfrag(&Bs[(wc * 32 + l15) * 200 + k0]);
      bf16x8 b1 = ldfrag(&Bs[(wc * 32 + 16 + l15) * 200 + k0]);
#pragma unroll
      for (int fr = 0; fr < 4; ++fr) {
        bf16x8 aa = ldfrag(&As[(wr * 64 + fr * 16 + l15) * 200 + k0]);
        acc[fr][0] = __builtin_amdgcn_mfma_f32_16x16x32_bf16(aa, b0, acc[fr][0], 0, 0, 0);
        acc[fr][1] = __builtin_amdgcn_mfma_f32_16x16x32_bf16(aa, b1, acc[fr][1], 0, 0, 0);
      }
    }
    __syncthreads();
#pragma unroll
    for (int fr = 0; fr < 4; ++fr)
#pragma unroll
      for (int fc = 0; fc < 2; ++fc)
#pragma unroll
        for (int r = 0; r < 4; ++r) {
          int row = m0 + wr * 64 + fr * 16 + hi * 4 + r;
          int col = j * 64 + wc * 32 + fc * 16 + l15;
          out[row * CDIM + col] = acc[fr][fc][r] + bias[col];
        }
  }
}

extern "C" void kernel_launch(void* const* d_in, const int* in_sizes, int n_in,
                              void* d_out, int out_size, void* d_ws, size_t ws_size,
                              hipStream_t stream) {
  const float* x      = (const float*)d_in[0];
  const float* mask   = (const float*)d_in[1];
  const float* qkv_w  = (const float*)d_in[2];
  const float* qkv_b  = (const float*)d_in[3];
  const float* out_w  = (const float*)d_in[4];
  const float* out_b  = (const float*)d_in[5];
  const float* table  = (const float*)d_in[6];
  const int*   relidx = (const int*)d_in[7];
  float* out = (float*)d_out;
  char* ws = (char*)d_ws;

  // ws layout (256B-aligned)
  const size_t off_bias = 0;                               // 57624 f32 = 230,496
  const size_t off_wqb  = 230656;                          // 110592 u16 = 221,184
  const size_t off_wob  = 451840;                          // 36864 u16 = 73,728
  const size_t off_qkv  = 525568;                          // 18*MROWS*32 u16 = 57,802,752
  const size_t off_ao   = off_qkv + 57802752;              // MROWS*192 u16 = 19,267,584
  float* biasHT = (float*)(ws + off_bias);
  unsigned short* wqb  = (unsigned short*)(ws + off_wqb);
  unsigned short* wob  = (unsigned short*)(ws + off_wob);
  unsigned short* qkvp = (unsigned short*)(ws + off_qkv);
  unsigned short* aop  = (unsigned short*)(ws + off_ao);

  k_prep<<<(PREP_TOT + 255) / 256, 256, 0, stream>>>(table, relidx, qkv_w, out_w,
                                                     biasHT, wqb, wob);
  k_qkv<<<MROWS / 128, 256, 0, stream>>>(x, wqb, qkv_b, qkvp);
  k_attn<<<BWIN * NH, 448, 0, stream>>>(qkvp, biasHT, mask, aop);
  k_proj<<<MROWS / 128, 256, 0, stream>>>(aop, wob, out_b, out);
}